// Round 18
// baseline (815.174 us; speedup 1.0000x reference)
//
#include <hip/hip_runtime.h>
#include <stdint.h>

#define VOCABN 8000
#define EE     300
#define HH     75
#define G4     300   // 4*H
#define TT     6
#define BB     256
#define SS     512
#define STARTT 4
#define STOPT  5
#define NEGV   (-10000.0f)
#define NCH    16    // CRF chunks
#define CHL    32    // steps per chunk

typedef __fp16 fp16x2 __attribute__((ext_vector_type(2)));
typedef __fp16 f16x8 __attribute__((ext_vector_type(8)));
typedef float f32x4 __attribute__((ext_vector_type(4)));
typedef unsigned int u32;
typedef unsigned short u16;

__device__ __forceinline__ float sigf(float x){
  return __builtin_amdgcn_rcpf(1.0f + __expf(-x));
}
__device__ __forceinline__ float tanhf_(float x){
  return __builtin_fmaf(__builtin_amdgcn_rcpf(1.0f + __expf(-2.0f * x)), 2.0f, -1.0f);
}
__device__ __forceinline__ float pk2(float a, float b){
  fp16x2 r = __builtin_amdgcn_cvt_pkrtz(a, b);
  return __builtin_bit_cast(float, r);
}
__device__ __forceinline__ float dot2pk(float a, float b, float c){
  asm("v_dot2_f32_f16 %0, %1, %2, %0" : "+v"(c) : "v"(a), "v"(b));
  return c;
}
// raw barrier: orders LDS, leaves global prefetches in flight
__device__ __forceinline__ void sync_lds(){
  __builtin_amdgcn_sched_barrier(0);
  asm volatile("s_waitcnt lgkmcnt(0)" ::: "memory");
  __builtin_amdgcn_s_barrier();
  __builtin_amdgcn_sched_barrier(0);
}

// ---------------- K1: MFMA f16 GEMM -> vxg[dir][v][g'] (permuted, f32 out) ---
__global__ __launch_bounds__(256) void k_gemm(
    const float* __restrict__ emb, const float* __restrict__ w_ih_f,
    const float* __restrict__ w_ih_b,
    const float* __restrict__ b_ih_f, const float* __restrict__ b_hh_f,
    const float* __restrict__ b_ih_b, const float* __restrict__ b_hh_b,
    float* __restrict__ vxg){
  __shared__ alignas(16) __fp16 bfrag[19 * 64 * 8];   // [gtile][lane][j]
  __shared__ float bias_sh[304];
  const int bx = blockIdx.x;
  const int dir = bx / 125;
  const int vblk = bx % 125;
  const int v0 = vblk * 64;
  const int tid = threadIdx.x;
  const int w = tid >> 6, lane = tid & 63;
  const int bb = lane & 15, q = lane >> 4;
  const float* wdir = dir ? w_ih_b : w_ih_f;

  for (int g = tid; g < 304; g += 256){
    float bi = 0.f;
    if (g < G4){
      int gs = (g & 3) * 75 + (g >> 2);
      bi = dir ? (b_ih_b[gs] + b_hh_b[gs]) : (b_ih_f[gs] + b_hh_f[gs]);
    }
    bias_sh[g] = bi;
  }
  if (tid < 16){
    int col = 12 + (tid & 3), qq = tid >> 2;
    *(u32*)&bfrag[(18 * 64 + qq * 16 + col) * 8]     = 0;
    *(u32*)&bfrag[(18 * 64 + qq * 16 + col) * 8 + 2] = 0;
    *(u32*)&bfrag[(18 * 64 + qq * 16 + col) * 8 + 4] = 0;
    *(u32*)&bfrag[(18 * 64 + qq * 16 + col) * 8 + 6] = 0;
  }

  f32x4 acc[19];
  #pragma unroll
  for (int t = 0; t < 19; ++t) acc[t] = (f32x4){0.f, 0.f, 0.f, 0.f};

  const float* arow = emb + (size_t)(v0 + 16 * w + bb) * EE;
  const int rstage = tid >> 3;
  const int sub = tid & 7;

  for (int c = 0; c < 10; ++c){
    f16x8 afrag;
    const int kb = 32 * c + 8 * q;
    if (c < 9){
      float4 x0 = *(const float4*)(arow + kb);
      float4 x1 = *(const float4*)(arow + kb + 4);
      afrag[0] = (__fp16)x0.x; afrag[1] = (__fp16)x0.y;
      afrag[2] = (__fp16)x0.z; afrag[3] = (__fp16)x0.w;
      afrag[4] = (__fp16)x1.x; afrag[5] = (__fp16)x1.y;
      afrag[6] = (__fp16)x1.z; afrag[7] = (__fp16)x1.w;
    } else {
      #pragma unroll
      for (int j = 0; j < 8; ++j)
        afrag[j] = (kb + j < EE) ? (__fp16)arow[kb + j] : (__fp16)0.f;
    }

    __syncthreads();
    for (int r0 = 0; r0 < 300; r0 += 32){
      int r = r0 + rstage;
      if (r < 300){
        int gsrc2 = (r & 3) * 75 + (r >> 2);
        const float* wr = wdir + (size_t)gsrc2 * EE;
        int e0 = 32 * c + 4 * sub;
        float4 xv;
        if (e0 + 3 < EE) xv = *(const float4*)(wr + e0);
        else {
          xv.x = (e0     < EE) ? wr[e0]     : 0.f;
          xv.y = (e0 + 1 < EE) ? wr[e0 + 1] : 0.f;
          xv.z = (e0 + 2 < EE) ? wr[e0 + 2] : 0.f;
          xv.w = (e0 + 3 < EE) ? wr[e0 + 3] : 0.f;
        }
        fp16x2 lo = __builtin_amdgcn_cvt_pkrtz(xv.x, xv.y);
        fp16x2 hi = __builtin_amdgcn_cvt_pkrtz(xv.z, xv.w);
        int t2 = r >> 4, col = r & 15;
        int qq = sub >> 1, j = 4 * (sub & 1);
        u32* dst = (u32*)&bfrag[(t2 * 64 + qq * 16 + col) * 8 + j];
        dst[0] = __builtin_bit_cast(u32, lo);
        dst[1] = __builtin_bit_cast(u32, hi);
      }
    }
    __syncthreads();

    #pragma unroll
    for (int t = 0; t < 19; ++t){
      f16x8 bf = *(const f16x8*)&bfrag[(t * 64 + lane) * 8];
      asm("v_mfma_f32_16x16x32_f16 %0, %1, %2, %0"
          : "+v"(acc[t]) : "v"(afrag), "v"(bf));
    }
  }

  const size_t obase = (size_t)dir * VOCABN * G4;
  #pragma unroll
  for (int t = 0; t < 19; ++t){
    int g = 16 * t + bb;
    if (g < G4){
      float bi = bias_sh[g];
      #pragma unroll
      for (int r = 0; r < 4; ++r){
        int v = v0 + 16 * w + 4 * q + r;
        vxg[obase + (size_t)v * G4 + g] = acc[t][r] + bi;
      }
    }
  }
}

// ---------------- K2: MFMA BiLSTM, 32 batch per block (2 interleaved sets) ---
// r17 restructure: each block runs TWO independent 16-batch sets; their
// dependent chains (ds_read -> MFMA -> transcendental ACT) interleave inside
// each wave, filling the ~90% stall cycles the single-set version measured.
// Weights (A-frags) shared between sets; one barrier per step kept.
__global__ __launch_bounds__(640) void k_lstm(
    const int* __restrict__ sentence, const float* __restrict__ vxg,
    const float* __restrict__ w_hh_f, const float* __restrict__ w_hh_b,
    const float* __restrict__ h0, const float* __restrict__ c0,
    const float* __restrict__ w_out, const float* __restrict__ b_out,
    float* __restrict__ featsF, float* __restrict__ featsB){
  __shared__ u16 tok_sh[SS * 32];                       // 32 KB
  __shared__ alignas(16) __fp16 hfrag[2][2][12 * 16 * 8]; // [buf][set] 12 KB
  const int bx = blockIdx.x;
  const int dir = bx >> 3, group = bx & 7;
  const int t = threadIdx.x;
  const int w = t >> 6, lane = t & 63;
  const int bb = lane & 15, q = lane >> 4;
  const int T0 = 2 * w, T1 = 2 * w + 1;
  const int rbA = 16 * T0 + 4 * q, rbB = 16 * T1 + 4 * q;
  const int hA = rbA >> 2, hB = rbB >> 2;
  const int bg0 = group * 32 + bb;          // set-0 batch
  const int bg1 = group * 32 + 16 + bb;     // set-1 batch
  const int wiA = w * 128 + bb * 8 + q;
  const int wiB = w * 128 + bb * 8 + 4 + q;

  for (int i = t; i < 2 * 2 * 12 * 16 * 4; i += 640) ((u32*)hfrag)[i] = 0;
  for (int i = t; i < 32 * SS; i += 640){
    int bq = i >> 9, s = i & 511;
    tok_sh[s * 32 + ((bq + s) & 31)] =
        (u16)sentence[(size_t)(group * 32 + bq) * SS + s];
  }
  __syncthreads();

  const float* whh = dir ? w_hh_b : w_hh_f;
  f16x8 a00, a01, a02, a10, a11, a12;
  #define BUILD_A(dst, T, c) { \
    int m = 16 * (T) + bb; int kb = 32 * (c) + 8 * q; \
    _Pragma("unroll") \
    for (int j = 0; j < 8; ++j){ \
      int kk = kb + j; float wv = 0.f; \
      if (kk < HH){ \
        if (m < 300) wv = whh[((m & 3) * 75 + (m >> 2)) * HH + kk]; \
        else if (m < 306) wv = w_out[(m - 300) * (2 * HH) + dir * HH + kk]; \
      } \
      dst[j] = (__fp16)wv; } }
  BUILD_A(a00, T0, 0) BUILD_A(a01, T0, 1) BUILD_A(a02, T0, 2)
  BUILD_A(a10, T1, 0) BUILD_A(a11, T1, 1) BUILD_A(a12, T1, 2)

  float cA0 = 0.f, cB0 = 0.f, cA1 = 0.f, cB1 = 0.f;
  if (hA < HH){
    cA0 = c0[((size_t)dir * BB + bg0) * HH + hA];
    cA1 = c0[((size_t)dir * BB + bg1) * HH + hA];
    hfrag[0][0][wiA] = (__fp16)h0[((size_t)dir * BB + bg0) * HH + hA];
    hfrag[0][1][wiA] = (__fp16)h0[((size_t)dir * BB + bg1) * HH + hA];
  }
  if (hB < HH){
    cB0 = c0[((size_t)dir * BB + bg0) * HH + hB];
    cB1 = c0[((size_t)dir * BB + bg1) * HH + hB];
    hfrag[0][0][wiB] = (__fp16)h0[((size_t)dir * BB + bg0) * HH + hB];
    hfrag[0][1][wiB] = (__fp16)h0[((size_t)dir * BB + bg1) * HH + hB];
  }
  const float bo0 = dir ? 0.f : b_out[0], bo1 = dir ? 0.f : b_out[1];
  const float bo2 = dir ? 0.f : b_out[2], bo3 = dir ? 0.f : b_out[3];
  const float bo4 = dir ? 0.f : b_out[4], bo5 = dir ? 0.f : b_out[5];
  __syncthreads();

  const float* vx = vxg + (size_t)dir * VOCABN * G4;
  float* feats = dir ? featsB : featsF;
  const float4 zf4 = {0.f, 0.f, 0.f, 0.f};

#define LOADXG2(dA0, dB0, dA1, dB1, kstep) { \
    if ((kstep) < SS){ \
      int sr_ = dir ? (SS - 1 - (kstep)) : (kstep); \
      int tk0_ = tok_sh[sr_ * 32 + ((bb + sr_) & 31)]; \
      int tk1_ = tok_sh[sr_ * 32 + ((bb + 16 + sr_) & 31)]; \
      const float* bs0_ = vx + (size_t)tk0_ * G4; \
      const float* bs1_ = vx + (size_t)tk1_ * G4; \
      dA0 = (hA < HH) ? *(const float4*)(bs0_ + rbA) : zf4; \
      dB0 = (hB < HH) ? *(const float4*)(bs0_ + rbB) : zf4; \
      dA1 = (hA < HH) ? *(const float4*)(bs1_ + rbA) : zf4; \
      dB1 = (hB < HH) ? *(const float4*)(bs1_ + rbB) : zf4; \
    } else { dA0 = zf4; dB0 = zf4; dA1 = zf4; dB1 = zf4; } }

  float4 curA0, curB0, curA1, curB1, nxA0, nxB0, nxA1, nxB1;
  float4 pA0, pB0, pA1, pB1;
  LOADXG2(curA0, curB0, curA1, curB1, 0)
  LOADXG2(nxA0, nxB0, nxA1, nxB1, 1)

  for (int k = 0; k <= SS; ++k){
    const __fp16* hq0 = hfrag[k & 1][0];
    const __fp16* hq1 = hfrag[k & 1][1];
    f16x8 b0s0 = *(const f16x8*)&hq0[(0 * 64 + lane) * 8];
    f16x8 b0s1 = *(const f16x8*)&hq1[(0 * 64 + lane) * 8];
    f16x8 b1s0 = *(const f16x8*)&hq0[(1 * 64 + lane) * 8];
    f16x8 b1s1 = *(const f16x8*)&hq1[(1 * 64 + lane) * 8];
    f16x8 b2s0 = *(const f16x8*)&hq0[(2 * 64 + lane) * 8];
    f16x8 b2s1 = *(const f16x8*)&hq1[(2 * 64 + lane) * 8];

    LOADXG2(pA0, pB0, pA1, pB1, k + 2)       // depth-2 xg prefetch

    f32x4 accA0 = {curA0.x, curA0.y, curA0.z, curA0.w};
    f32x4 accA1 = {curA1.x, curA1.y, curA1.z, curA1.w};
    f32x4 accB0 = {curB0.x, curB0.y, curB0.z, curB0.w};
    f32x4 accB1 = {curB1.x, curB1.y, curB1.z, curB1.w};
    asm("v_mfma_f32_16x16x32_f16 %0, %1, %2, %0" : "+v"(accA0) : "a"(a00), "v"(b0s0));
    asm("v_mfma_f32_16x16x32_f16 %0, %1, %2, %0" : "+v"(accA1) : "a"(a00), "v"(b0s1));
    asm("v_mfma_f32_16x16x32_f16 %0, %1, %2, %0" : "+v"(accB0) : "a"(a10), "v"(b0s0));
    asm("v_mfma_f32_16x16x32_f16 %0, %1, %2, %0" : "+v"(accB1) : "a"(a10), "v"(b0s1));
    asm("v_mfma_f32_16x16x32_f16 %0, %1, %2, %0" : "+v"(accA0) : "a"(a01), "v"(b1s0));
    asm("v_mfma_f32_16x16x32_f16 %0, %1, %2, %0" : "+v"(accA1) : "a"(a01), "v"(b1s1));
    asm("v_mfma_f32_16x16x32_f16 %0, %1, %2, %0" : "+v"(accB0) : "a"(a11), "v"(b1s0));
    asm("v_mfma_f32_16x16x32_f16 %0, %1, %2, %0" : "+v"(accB1) : "a"(a11), "v"(b1s1));
    asm("v_mfma_f32_16x16x32_f16 %0, %1, %2, %0" : "+v"(accA0) : "a"(a02), "v"(b2s0));
    asm("v_mfma_f32_16x16x32_f16 %0, %1, %2, %0" : "+v"(accA1) : "a"(a02), "v"(b2s1));
    asm("v_mfma_f32_16x16x32_f16 %0, %1, %2, %0" : "+v"(accB0) : "a"(a12), "v"(b2s0));
    asm("v_mfma_f32_16x16x32_f16 %0, %1, %2, %0" : "+v"(accB1) : "a"(a12), "v"(b2s1));

    __fp16* hw0 = hfrag[(k & 1) ^ 1][0];
    __fp16* hw1 = hfrag[(k & 1) ^ 1][1];
    if (k < SS){
      if (hA < HH){
        { float gi = accA0.x, gf = accA0.y, gg = accA0.z, go = accA0.w;
          cA0 = sigf(gf) * cA0 + sigf(gi) * tanhf_(gg);
          hw0[wiA] = (__fp16)(sigf(go) * tanhf_(cA0)); }
        { float gi = accA1.x, gf = accA1.y, gg = accA1.z, go = accA1.w;
          cA1 = sigf(gf) * cA1 + sigf(gi) * tanhf_(gg);
          hw1[wiA] = (__fp16)(sigf(go) * tanhf_(cA1)); }
      }
      if (hB < HH){
        { float gi = accB0.x, gf = accB0.y, gg = accB0.z, go = accB0.w;
          cB0 = sigf(gf) * cB0 + sigf(gi) * tanhf_(gg);
          hw0[wiB] = (__fp16)(sigf(go) * tanhf_(cB0)); }
        { float gi = accB1.x, gf = accB1.y, gg = accB1.z, go = accB1.w;
          cB1 = sigf(gf) * cB1 + sigf(gi) * tanhf_(gg);
          hw1[wiB] = (__fp16)(sigf(go) * tanhf_(cB1)); }
      }
    }
    if (k >= 1){
      int ps = dir ? (SS - k) : (k - 1);
      if (rbA == 300){                       // feat rows 0..3 (wave 9, q=3)
        float* fb0 = feats + ((size_t)ps * BB + bg0) * TT;
        float* fb1 = feats + ((size_t)ps * BB + bg1) * TT;
        float2 u01 = {accA0.x + bo0, accA0.y + bo1};
        float2 u23 = {accA0.z + bo2, accA0.w + bo3};
        *(float2*)fb0 = u01; *(float2*)(fb0 + 2) = u23;
        float2 v01 = {accA1.x + bo0, accA1.y + bo1};
        float2 v23 = {accA1.z + bo2, accA1.w + bo3};
        *(float2*)fb1 = v01; *(float2*)(fb1 + 2) = v23;
      }
      if (rbB == 304){                       // feat rows 4..5 (wave 9, q=0)
        float* fb0 = feats + ((size_t)ps * BB + bg0) * TT;
        float* fb1 = feats + ((size_t)ps * BB + bg1) * TT;
        float2 u45 = {accB0.x + bo4, accB0.y + bo5};
        *(float2*)(fb0 + 4) = u45;
        float2 v45 = {accB1.x + bo4, accB1.y + bo5};
        *(float2*)(fb1 + 4) = v45;
      }
    }
    curA0 = nxA0; curB0 = nxB0; curA1 = nxA1; curB1 = nxB1;
    nxA0 = pA0;  nxB0 = pB0;  nxA1 = pA1;  nxB1 = pB1;
    sync_lds();
  }
}

// ---------------- K3a: CRF chunked alpha-scan + gold partials ----------------
#define LOADSTAGE(X0,X1,X2,Y0,Y1,Y2, srow) do{ \
  int _r = (srow); if (_r >= SS) _r = 0; \
  const float2* _pF = (const float2*)(featsF + ((size_t)_r * BB + b) * TT); \
  const float2* _pB = (const float2*)(featsB + ((size_t)_r * BB + b) * TT); \
  X0 = _pF[0]; X1 = _pF[1]; X2 = _pF[2]; \
  Y0 = _pB[0]; Y1 = _pB[1]; Y2 = _pB[2]; }while(0)

#define ASTEP(X0,X1,X2,Y0,Y1,Y2, srow) do{ \
  float F0 = X0.x + Y0.x, F1 = X0.y + Y0.y, F2 = X1.x + Y1.x; \
  float F3 = X1.y + Y1.y, F4 = X2.x + Y2.x, F5 = X2.y + Y2.y; \
  float M = fmaxf(fmaxf(fmaxf(a0,a1),fmaxf(a2,a3)),fmaxf(a4,a5)); \
  float p01 = pk2(__expf(a0-M), __expf(a1-M)); \
  float p23 = pk2(__expf(a2-M), __expf(a3-M)); \
  float p45 = pk2(__expf(a4-M), __expf(a5-M)); \
  float s0 = dot2pk(p45, Tq2,  dot2pk(p23, Tq1,  dot2pk(p01, Tq0,  0.f))); \
  float s1 = dot2pk(p45, Tq5,  dot2pk(p23, Tq4,  dot2pk(p01, Tq3,  0.f))); \
  float s2 = dot2pk(p45, Tq8,  dot2pk(p23, Tq7,  dot2pk(p01, Tq6,  0.f))); \
  float s3 = dot2pk(p45, Tq11, dot2pk(p23, Tq10, dot2pk(p01, Tq9,  0.f))); \
  float s4 = dot2pk(p45, Tq14, dot2pk(p23, Tq13, dot2pk(p01, Tq12, 0.f))); \
  float s5 = dot2pk(p45, Tq17, dot2pk(p23, Tq16, dot2pk(p01, Tq15, 0.f))); \
  a0 = M + __logf(fmaxf(s0, 1e-37f)) + F0;  a1 = M + __logf(fmaxf(s1, 1e-37f)) + F1; \
  a2 = M + __logf(fmaxf(s2, 1e-37f)) + F2;  a3 = M + __logf(fmaxf(s3, 1e-37f)) + F3; \
  a4 = M + __logf(fmaxf(s4, 1e-37f)) + F4;  a5 = M + __logf(fmaxf(s5, 1e-37f)) + F5; \
  LOADSTAGE(X0,X1,X2,Y0,Y1,Y2, (srow) + 2); }while(0)

__global__ __launch_bounds__(256) void k_crf_scan(
    const float* __restrict__ featsF, const float* __restrict__ featsB,
    const float* __restrict__ trans, const int* __restrict__ tags,
    float* __restrict__ crfM, float* __restrict__ pgold){
  __shared__ float tr_sh[36];
  __shared__ u32 etp_sh[18];
  const int tid = threadIdx.x;
  if (tid < 36) tr_sh[tid] = trans[tid];
  if (tid < 18) etp_sh[tid] = __float_as_uint(
      pk2(__expf(trans[2 * tid]), __expf(trans[2 * tid + 1])));
  __syncthreads();
  const int bx = blockIdx.x;

  if (bx < 96){
    const int g = bx * 256 + tid;
    const int s0i = g % 6;
    const int c = (g / 6) % NCH;
    const int b = g / (6 * NCH);
    const int cbase = c * CHL;

    float Tq0=__int_as_float(etp_sh[0]),  Tq1=__int_as_float(etp_sh[1]),
          Tq2=__int_as_float(etp_sh[2]),  Tq3=__int_as_float(etp_sh[3]),
          Tq4=__int_as_float(etp_sh[4]),  Tq5=__int_as_float(etp_sh[5]),
          Tq6=__int_as_float(etp_sh[6]),  Tq7=__int_as_float(etp_sh[7]),
          Tq8=__int_as_float(etp_sh[8]),  Tq9=__int_as_float(etp_sh[9]),
          Tq10=__int_as_float(etp_sh[10]), Tq11=__int_as_float(etp_sh[11]),
          Tq12=__int_as_float(etp_sh[12]), Tq13=__int_as_float(etp_sh[13]),
          Tq14=__int_as_float(etp_sh[14]), Tq15=__int_as_float(etp_sh[15]),
          Tq16=__int_as_float(etp_sh[16]), Tq17=__int_as_float(etp_sh[17]);

    float a0 = (s0i == 0) ? 0.f : NEGV, a1 = (s0i == 1) ? 0.f : NEGV;
    float a2 = (s0i == 2) ? 0.f : NEGV, a3 = (s0i == 3) ? 0.f : NEGV;
    float a4 = (s0i == 4) ? 0.f : NEGV, a5 = (s0i == 5) ? 0.f : NEGV;

    float2 xA0,xA1,xA2,yA0,yA1,yA2, xB0,xB1,xB2,yB0,yB1,yB2;
    LOADSTAGE(xA0,xA1,xA2,yA0,yA1,yA2, cbase + 0);
    LOADSTAGE(xB0,xB1,xB2,yB0,yB1,yB2, cbase + 1);
    for (int s = 0; s < CHL; s += 2){
      ASTEP(xA0,xA1,xA2,yA0,yA1,yA2, cbase + s);
      ASTEP(xB0,xB1,xB2,yB0,yB1,yB2, cbase + s + 1);
    }
    float* mrow = crfM + ((size_t)(b * NCH + c) * 6 + s0i) * 6;
    mrow[0] = a0; mrow[1] = a1; mrow[2] = a2;
    mrow[3] = a3; mrow[4] = a4; mrow[5] = a5;
  } else {
    const int g2 = (bx - 96) * 256 + tid;
    const int b = g2 / NCH;
    const int c = g2 % NCH;
    const int* tg = tags + (size_t)b * SS + c * CHL;
    int prev = (c == 0) ? STARTT : tg[-1];
    float acc = 0.f;
    #pragma unroll 4
    for (int s = 0; s < CHL; ++s){
      int ct = tg[s];
      size_t fo = (size_t)(c * CHL + s) * BB * TT + (size_t)b * TT + ct;
      acc += tr_sh[ct * 6 + prev] + featsF[fo] + featsB[fo];
      prev = ct;
    }
    pgold[b * NCH + c] = acc;
  }
}

// ---------------- K3b: combine 16 chunk matrices + finish -------------------
__global__ __launch_bounds__(64) void k_crf_comb(
    const float* __restrict__ crfM, const float* __restrict__ pgold,
    const float* __restrict__ trans, const int* __restrict__ tags,
    float* __restrict__ out){
  const int b = blockIdx.x * 64 + threadIdx.x;
  float v0 = NEGV, v1 = NEGV, v2 = NEGV, v3 = NEGV, v4 = 0.f, v5 = NEGV;
  for (int c = 0; c < NCH; ++c){
    const float* mb = crfM + (size_t)(b * NCH + c) * 36;
    float n[6];
    #pragma unroll
    for (int j = 0; j < 6; ++j){
      float t0 = v0 + mb[0 * 6 + j], t1 = v1 + mb[1 * 6 + j];
      float t2 = v2 + mb[2 * 6 + j], t3 = v3 + mb[3 * 6 + j];
      float t4 = v4 + mb[4 * 6 + j], t5 = v5 + mb[5 * 6 + j];
      float m = fmaxf(fmaxf(fmaxf(t0,t1),fmaxf(t2,t3)),fmaxf(t4,t5));
      float s = __expf(t0-m)+__expf(t1-m)+__expf(t2-m)
              + __expf(t3-m)+__expf(t4-m)+__expf(t5-m);
      n[j] = m + __logf(s);
    }
    v0 = n[0]; v1 = n[1]; v2 = n[2]; v3 = n[3]; v4 = n[4]; v5 = n[5];
  }
  float z0 = v0 + trans[30], z1 = v1 + trans[31], z2 = v2 + trans[32];
  float z3 = v3 + trans[33], z4 = v4 + trans[34], z5 = v5 + trans[35];
  float M2 = fmaxf(fmaxf(fmaxf(z0,z1),fmaxf(z2,z3)),fmaxf(z4,z5));
  float ss = __expf(z0-M2)+__expf(z1-M2)+__expf(z2-M2)
           + __expf(z3-M2)+__expf(z4-M2)+__expf(z5-M2);
  float fwd = M2 + __logf(ss);

  float gold = trans[STOPT * 6 + tags[(size_t)b * SS + SS - 1]];
  #pragma unroll
  for (int c = 0; c < NCH; ++c) gold += pgold[b * NCH + c];
  out[b] = fwd - gold;
}

// ---------------- launch -----------------------------------------------------
extern "C" void kernel_launch(void* const* d_in, const int* in_sizes, int n_in,
                              void* d_out, int out_size, void* d_ws, size_t ws_size,
                              hipStream_t stream){
  const int*   sentence = (const int*)  d_in[0];
  const int*   tags     = (const int*)  d_in[1];
  const float* emb      = (const float*)d_in[2];
  const float* w_ih_f   = (const float*)d_in[3];
  const float* w_hh_f   = (const float*)d_in[4];
  const float* b_ih_f   = (const float*)d_in[5];
  const float* b_hh_f   = (const float*)d_in[6];
  const float* w_ih_b   = (const float*)d_in[7];
  const float* w_hh_b   = (const float*)d_in[8];
  const float* b_ih_b   = (const float*)d_in[9];
  const float* b_hh_b   = (const float*)d_in[10];
  const float* h0       = (const float*)d_in[11];
  const float* c0       = (const float*)d_in[12];
  const float* w_out    = (const float*)d_in[13];
  const float* b_out    = (const float*)d_in[14];
  const float* trans    = (const float*)d_in[15];
  float* out = (float*)d_out;

  float* ws = (float*)d_ws;
  float* vxg    = ws;                                 // [2][8000][300] (permuted)
  float* featsF = vxg + (size_t)2 * VOCABN * G4;      // [512][256][6]
  float* featsB = featsF + (size_t)SS * BB * TT;      // [512][256][6]
  float* crfM   = featsB + (size_t)SS * BB * TT;      // [256][16][6][6]
  float* pgold  = crfM + (size_t)BB * NCH * 36;       // [256][16]

  k_gemm<<<2 * 125, 256, 0, stream>>>(emb, w_ih_f, w_ih_b,
                                      b_ih_f, b_hh_f, b_ih_b, b_hh_b, vxg);
  k_lstm<<<16, 640, 0, stream>>>(sentence, vxg, w_hh_f, w_hh_b, h0, c0, w_out, b_out,
                                 featsF, featsB);
  k_crf_scan<<<96 + 16, 256, 0, stream>>>(featsF, featsB, trans, tags, crfM, pgold);
  k_crf_comb<<<BB / 64, 64, 0, stream>>>(crfM, pgold, trans, tags, out);
}

// Round 19
// 460.253 us; speedup vs baseline: 1.7711x; 1.7711x over previous
//
#include <hip/hip_runtime.h>
#include <stdint.h>

#define VOCABN 8000
#define EE     300
#define HH     75
#define G4     300   // 4*H
#define TT     6
#define BB     256
#define SS     512
#define STARTT 4
#define STOPT  5
#define NEGV   (-10000.0f)
#define NCH    16    // CRF chunks
#define CHL    32    // steps per chunk

typedef __fp16 fp16x2 __attribute__((ext_vector_type(2)));
typedef __fp16 f16x8 __attribute__((ext_vector_type(8)));
typedef float f32x4 __attribute__((ext_vector_type(4)));
typedef unsigned int u32;

__device__ __forceinline__ float sigf(float x){
  return __builtin_amdgcn_rcpf(1.0f + __expf(-x));
}
__device__ __forceinline__ float tanhf_(float x){
  return __builtin_fmaf(__builtin_amdgcn_rcpf(1.0f + __expf(-2.0f * x)), 2.0f, -1.0f);
}
__device__ __forceinline__ float pk2(float a, float b){
  fp16x2 r = __builtin_amdgcn_cvt_pkrtz(a, b);
  return __builtin_bit_cast(float, r);
}
__device__ __forceinline__ float dot2pk(float a, float b, float c){
  asm("v_dot2_f32_f16 %0, %1, %2, %0" : "+v"(c) : "v"(a), "v"(b));
  return c;
}
// raw barrier: orders LDS, leaves global prefetches in flight
__device__ __forceinline__ void sync_lds(){
  __builtin_amdgcn_sched_barrier(0);
  asm volatile("s_waitcnt lgkmcnt(0)" ::: "memory");
  __builtin_amdgcn_s_barrier();
  __builtin_amdgcn_sched_barrier(0);
}

// ---------------- K1: MFMA f16 GEMM -> vxg[dir][v][g'] (permuted, f32 out) ---
// Coalesced B-staging (r15 fix, measured ~20us). Mapping HW-validated r14.
__global__ __launch_bounds__(256) void k_gemm(
    const float* __restrict__ emb, const float* __restrict__ w_ih_f,
    const float* __restrict__ w_ih_b,
    const float* __restrict__ b_ih_f, const float* __restrict__ b_hh_f,
    const float* __restrict__ b_ih_b, const float* __restrict__ b_hh_b,
    float* __restrict__ vxg){
  __shared__ alignas(16) __fp16 bfrag[19 * 64 * 8];   // [gtile][lane][j]
  __shared__ float bias_sh[304];
  const int bx = blockIdx.x;
  const int dir = bx / 125;
  const int vblk = bx % 125;
  const int v0 = vblk * 64;
  const int tid = threadIdx.x;
  const int w = tid >> 6, lane = tid & 63;
  const int bb = lane & 15, q = lane >> 4;
  const float* wdir = dir ? w_ih_b : w_ih_f;

  for (int g = tid; g < 304; g += 256){
    float bi = 0.f;
    if (g < G4){
      int gs = (g & 3) * 75 + (g >> 2);
      bi = dir ? (b_ih_b[gs] + b_hh_b[gs]) : (b_ih_f[gs] + b_hh_f[gs]);
    }
    bias_sh[g] = bi;
  }
  // zero the 4 never-staged B rows (g 300..303, tile 18 cols 12..15) once
  if (tid < 16){
    int col = 12 + (tid & 3), qq = tid >> 2;
    *(u32*)&bfrag[(18 * 64 + qq * 16 + col) * 8]     = 0;
    *(u32*)&bfrag[(18 * 64 + qq * 16 + col) * 8 + 2] = 0;
    *(u32*)&bfrag[(18 * 64 + qq * 16 + col) * 8 + 4] = 0;
    *(u32*)&bfrag[(18 * 64 + qq * 16 + col) * 8 + 6] = 0;
  }

  f32x4 acc[19];
  #pragma unroll
  for (int t = 0; t < 19; ++t) acc[t] = (f32x4){0.f, 0.f, 0.f, 0.f};

  const float* arow = emb + (size_t)(v0 + 16 * w + bb) * EE;
  const int rstage = tid >> 3;      // g-row this thread helps stage
  const int sub = tid & 7;          // float4 slot within the 32-wide chunk

  for (int c = 0; c < 10; ++c){
    // ---- A fragment (global f32 -> f16x8), rows are v = v0+16w+bb ----
    f16x8 afrag;
    const int kb = 32 * c + 8 * q;
    if (c < 9){
      float4 x0 = *(const float4*)(arow + kb);
      float4 x1 = *(const float4*)(arow + kb + 4);
      afrag[0] = (__fp16)x0.x; afrag[1] = (__fp16)x0.y;
      afrag[2] = (__fp16)x0.z; afrag[3] = (__fp16)x0.w;
      afrag[4] = (__fp16)x1.x; afrag[5] = (__fp16)x1.y;
      afrag[6] = (__fp16)x1.z; afrag[7] = (__fp16)x1.w;
    } else {
      #pragma unroll
      for (int j = 0; j < 8; ++j)
        afrag[j] = (kb + j < EE) ? (__fp16)arow[kb + j] : (__fp16)0.f;
    }

    // ---- stage B chunk, COALESCED: 8 threads per g-row, float4 each ----
    __syncthreads();   // protect bfrag reuse from previous chunk's MFMAs
    for (int r0 = 0; r0 < 300; r0 += 32){
      int r = r0 + rstage;
      if (r < 300){
        int gsrc2 = (r & 3) * 75 + (r >> 2);
        const float* wr = wdir + (size_t)gsrc2 * EE;
        int e0 = 32 * c + 4 * sub;
        float4 xv;
        if (e0 + 3 < EE) xv = *(const float4*)(wr + e0);
        else {
          xv.x = (e0     < EE) ? wr[e0]     : 0.f;
          xv.y = (e0 + 1 < EE) ? wr[e0 + 1] : 0.f;
          xv.z = (e0 + 2 < EE) ? wr[e0 + 2] : 0.f;
          xv.w = (e0 + 3 < EE) ? wr[e0 + 3] : 0.f;
        }
        fp16x2 lo = __builtin_amdgcn_cvt_pkrtz(xv.x, xv.y);
        fp16x2 hi = __builtin_amdgcn_cvt_pkrtz(xv.z, xv.w);
        int t2 = r >> 4, col = r & 15;
        int qq = sub >> 1, j = 4 * (sub & 1);
        u32* dst = (u32*)&bfrag[(t2 * 64 + qq * 16 + col) * 8 + j];
        dst[0] = __builtin_bit_cast(u32, lo);
        dst[1] = __builtin_bit_cast(u32, hi);
      }
    }
    __syncthreads();

    // ---- 19 MFMAs against the staged chunk ----
    #pragma unroll
    for (int t = 0; t < 19; ++t){
      f16x8 bf = *(const f16x8*)&bfrag[(t * 64 + lane) * 8];
      asm("v_mfma_f32_16x16x32_f16 %0, %1, %2, %0"
          : "+v"(acc[t]) : "v"(afrag), "v"(bf));
    }
  }

  const size_t obase = (size_t)dir * VOCABN * G4;
  #pragma unroll
  for (int t = 0; t < 19; ++t){
    int g = 16 * t + bb;
    if (g < G4){
      float bi = bias_sh[g];
      #pragma unroll
      for (int r = 0; r < 4; ++r){
        int v = v0 + 16 * w + 4 * q + r;
        vxg[obase + (size_t)v * G4 + g] = acc[t][r] + bi;
      }
    }
  }
}

// ---------------- K2: MFMA BiLSTM, 16 batch per block (r16 = measured best) --
// h in MFMA B-FRAGMENT-ORDER LDS (conflict-free reads at byte addr lane*16);
// acc initialized with the prefetched xg quad (free C-operand). 32 blocks x
// 10 waves, depth-2 prefetch. Seven alternatives bracketed worse (r10-r18).
__global__ __launch_bounds__(640) void k_lstm(
    const int* __restrict__ sentence, const float* __restrict__ vxg,
    const float* __restrict__ w_hh_f, const float* __restrict__ w_hh_b,
    const float* __restrict__ h0, const float* __restrict__ c0,
    const float* __restrict__ w_out, const float* __restrict__ b_out,
    float* __restrict__ featsF, float* __restrict__ featsB){
  __shared__ int tok_sh[SS * 16];
  __shared__ alignas(16) __fp16 hfrag[2][12 * 16 * 8];   // [buf][k>>3][bb][k&7]
  const int bx = blockIdx.x;
  const int dir = bx >> 4, group = bx & 15;
  const int t = threadIdx.x;
  const int w = t >> 6, lane = t & 63;
  const int bb = lane & 15, q = lane >> 4;
  const int T0 = 2 * w, T1 = 2 * w + 1;
  const int rbA = 16 * T0 + 4 * q, rbB = 16 * T1 + 4 * q;
  const int hA = rbA >> 2, hB = rbB >> 2;      // hA = 8w+q, hB = 8w+4+q
  const int bglob = group * 16 + bb;
  const int wiA = w * 128 + bb * 8 + q;        // fragment-order write indices
  const int wiB = w * 128 + bb * 8 + 4 + q;

  for (int i = t; i < 2 * 12 * 16 * 4; i += 640) ((u32*)hfrag)[i] = 0;
  for (int i = t; i < 16 * SS; i += 640){
    int bq = i >> 9, s = i & 511;
    tok_sh[s * 16 + ((bq + s) & 15)] = sentence[(size_t)(group * 16 + bq) * SS + s];
  }
  __syncthreads();

  const float* whh = dir ? w_hh_b : w_hh_f;
  f16x8 a00, a01, a02, a10, a11, a12;
  #define BUILD_A(dst, T, c) { \
    int m = 16 * (T) + bb; int kb = 32 * (c) + 8 * q; \
    _Pragma("unroll") \
    for (int j = 0; j < 8; ++j){ \
      int kk = kb + j; float wv = 0.f; \
      if (kk < HH){ \
        if (m < 300) wv = whh[((m & 3) * 75 + (m >> 2)) * HH + kk]; \
        else if (m < 306) wv = w_out[(m - 300) * (2 * HH) + dir * HH + kk]; \
      } \
      dst[j] = (__fp16)wv; } }
  BUILD_A(a00, T0, 0) BUILD_A(a01, T0, 1) BUILD_A(a02, T0, 2)
  BUILD_A(a10, T1, 0) BUILD_A(a11, T1, 1) BUILD_A(a12, T1, 2)

  float cA = 0.f, cB = 0.f;
  if (hA < HH){
    cA = c0[((size_t)dir * BB + bglob) * HH + hA];
    hfrag[0][wiA] = (__fp16)h0[((size_t)dir * BB + bglob) * HH + hA];
  }
  if (hB < HH){
    cB = c0[((size_t)dir * BB + bglob) * HH + hB];
    hfrag[0][wiB] = (__fp16)h0[((size_t)dir * BB + bglob) * HH + hB];
  }
  const float bo0 = dir ? 0.f : b_out[0], bo1 = dir ? 0.f : b_out[1];
  const float bo2 = dir ? 0.f : b_out[2], bo3 = dir ? 0.f : b_out[3];
  const float bo4 = dir ? 0.f : b_out[4], bo5 = dir ? 0.f : b_out[5];
  __syncthreads();

  const float* vx = vxg + (size_t)dir * VOCABN * G4;
  float* feats = dir ? featsB : featsF;
  const float4 zf4 = {0.f, 0.f, 0.f, 0.f};

  float4 cur0 = zf4, cur1 = zf4, nx0 = zf4, nx1 = zf4;
  {
    int p = dir ? (SS - 1) : 0;
    int tk = tok_sh[p * 16 + ((bb + p) & 15)];
    const float* base = vx + (size_t)tk * G4;
    if (hA < HH) cur0 = *(const float4*)(base + rbA);
    if (hB < HH) cur1 = *(const float4*)(base + rbB);
    p = dir ? (SS - 2) : 1;
    tk = tok_sh[p * 16 + ((bb + p) & 15)];
    base = vx + (size_t)tk * G4;
    if (hA < HH) nx0 = *(const float4*)(base + rbA);
    if (hB < HH) nx1 = *(const float4*)(base + rbB);
  }

  for (int k = 0; k <= SS; ++k){
    const __fp16* hq = hfrag[k & 1];
    f16x8 b0 = *(const f16x8*)&hq[(0 * 64 + lane) * 8];   // byte addr = lane*16
    f16x8 b1 = *(const f16x8*)&hq[(1 * 64 + lane) * 8];
    f16x8 b2 = *(const f16x8*)&hq[(2 * 64 + lane) * 8];

    float4 p0 = zf4, p1 = zf4;
    if (k + 2 < SS){                        // depth-2 xg prefetch
      int p = dir ? (SS - 3 - k) : (k + 2);
      int tk = tok_sh[p * 16 + ((bb + p) & 15)];
      const float* base = vx + (size_t)tk * G4;
      if (hA < HH) p0 = *(const float4*)(base + rbA);
      if (hB < HH) p1 = *(const float4*)(base + rbB);
    }

    // acc initialized with xg quad (C-operand is free in MFMA)
    f32x4 acc0 = {cur0.x, cur0.y, cur0.z, cur0.w};
    f32x4 acc1 = {cur1.x, cur1.y, cur1.z, cur1.w};
    asm("v_mfma_f32_16x16x32_f16 %0, %1, %2, %0" : "+v"(acc0) : "a"(a00), "v"(b0));
    asm("v_mfma_f32_16x16x32_f16 %0, %1, %2, %0" : "+v"(acc1) : "a"(a10), "v"(b0));
    asm("v_mfma_f32_16x16x32_f16 %0, %1, %2, %0" : "+v"(acc0) : "a"(a01), "v"(b1));
    asm("v_mfma_f32_16x16x32_f16 %0, %1, %2, %0" : "+v"(acc1) : "a"(a11), "v"(b1));
    asm("v_mfma_f32_16x16x32_f16 %0, %1, %2, %0" : "+v"(acc0) : "a"(a02), "v"(b2));
    asm("v_mfma_f32_16x16x32_f16 %0, %1, %2, %0" : "+v"(acc1) : "a"(a12), "v"(b2));

    __fp16* hw = hfrag[(k & 1) ^ 1];
    if (k < SS){
      if (hA < HH){
        float gi = acc0.x, gf = acc0.y, gg = acc0.z, go = acc0.w;
        cA = sigf(gf) * cA + sigf(gi) * tanhf_(gg);
        hw[wiA] = (__fp16)(sigf(go) * tanhf_(cA));
      }
      if (hB < HH){
        float gi = acc1.x, gf = acc1.y, gg = acc1.z, go = acc1.w;
        cB = sigf(gf) * cB + sigf(gi) * tanhf_(gg);
        hw[wiB] = (__fp16)(sigf(go) * tanhf_(cB));
      }
    }
    if (k >= 1){
      if (rbA == 300){                       // feat rows 0..3 (wave 9, q=3)
        int ps = dir ? (SS - k) : (k - 1);
        float* fb = feats + ((size_t)ps * BB + bglob) * TT;
        float2 v01 = {acc0.x + bo0, acc0.y + bo1};
        float2 v23 = {acc0.z + bo2, acc0.w + bo3};
        *(float2*)fb = v01;
        *(float2*)(fb + 2) = v23;
      }
      if (rbB == 304){                       // feat rows 4..5 (wave 9, q=0)
        int ps = dir ? (SS - k) : (k - 1);
        float* fb = feats + ((size_t)ps * BB + bglob) * TT;
        float2 v45 = {acc1.x + bo4, acc1.y + bo5};
        *(float2*)(fb + 4) = v45;
      }
    }
    cur0 = nx0; cur1 = nx1; nx0 = p0; nx1 = p1;
    sync_lds();
  }
}

// ---------------- K3a: CRF chunked alpha-scan + gold partials ----------------
#define LOADSTAGE(X0,X1,X2,Y0,Y1,Y2, srow) do{ \
  int _r = (srow); if (_r >= SS) _r = 0; \
  const float2* _pF = (const float2*)(featsF + ((size_t)_r * BB + b) * TT); \
  const float2* _pB = (const float2*)(featsB + ((size_t)_r * BB + b) * TT); \
  X0 = _pF[0]; X1 = _pF[1]; X2 = _pF[2]; \
  Y0 = _pB[0]; Y1 = _pB[1]; Y2 = _pB[2]; }while(0)

#define ASTEP(X0,X1,X2,Y0,Y1,Y2, srow) do{ \
  float F0 = X0.x + Y0.x, F1 = X0.y + Y0.y, F2 = X1.x + Y1.x; \
  float F3 = X1.y + Y1.y, F4 = X2.x + Y2.x, F5 = X2.y + Y2.y; \
  float M = fmaxf(fmaxf(fmaxf(a0,a1),fmaxf(a2,a3)),fmaxf(a4,a5)); \
  float p01 = pk2(__expf(a0-M), __expf(a1-M)); \
  float p23 = pk2(__expf(a2-M), __expf(a3-M)); \
  float p45 = pk2(__expf(a4-M), __expf(a5-M)); \
  float s0 = dot2pk(p45, Tq2,  dot2pk(p23, Tq1,  dot2pk(p01, Tq0,  0.f))); \
  float s1 = dot2pk(p45, Tq5,  dot2pk(p23, Tq4,  dot2pk(p01, Tq3,  0.f))); \
  float s2 = dot2pk(p45, Tq8,  dot2pk(p23, Tq7,  dot2pk(p01, Tq6,  0.f))); \
  float s3 = dot2pk(p45, Tq11, dot2pk(p23, Tq10, dot2pk(p01, Tq9,  0.f))); \
  float s4 = dot2pk(p45, Tq14, dot2pk(p23, Tq13, dot2pk(p01, Tq12, 0.f))); \
  float s5 = dot2pk(p45, Tq17, dot2pk(p23, Tq16, dot2pk(p01, Tq15, 0.f))); \
  a0 = M + __logf(fmaxf(s0, 1e-37f)) + F0;  a1 = M + __logf(fmaxf(s1, 1e-37f)) + F1; \
  a2 = M + __logf(fmaxf(s2, 1e-37f)) + F2;  a3 = M + __logf(fmaxf(s3, 1e-37f)) + F3; \
  a4 = M + __logf(fmaxf(s4, 1e-37f)) + F4;  a5 = M + __logf(fmaxf(s5, 1e-37f)) + F5; \
  LOADSTAGE(X0,X1,X2,Y0,Y1,Y2, (srow) + 2); }while(0)

__global__ __launch_bounds__(256) void k_crf_scan(
    const float* __restrict__ featsF, const float* __restrict__ featsB,
    const float* __restrict__ trans, const int* __restrict__ tags,
    float* __restrict__ crfM, float* __restrict__ pgold){
  __shared__ float tr_sh[36];
  __shared__ u32 etp_sh[18];
  const int tid = threadIdx.x;
  if (tid < 36) tr_sh[tid] = trans[tid];
  if (tid < 18) etp_sh[tid] = __float_as_uint(
      pk2(__expf(trans[2 * tid]), __expf(trans[2 * tid + 1])));
  __syncthreads();
  const int bx = blockIdx.x;

  if (bx < 96){
    const int g = bx * 256 + tid;
    const int s0i = g % 6;
    const int c = (g / 6) % NCH;
    const int b = g / (6 * NCH);
    const int cbase = c * CHL;

    float Tq0=__int_as_float(etp_sh[0]),  Tq1=__int_as_float(etp_sh[1]),
          Tq2=__int_as_float(etp_sh[2]),  Tq3=__int_as_float(etp_sh[3]),
          Tq4=__int_as_float(etp_sh[4]),  Tq5=__int_as_float(etp_sh[5]),
          Tq6=__int_as_float(etp_sh[6]),  Tq7=__int_as_float(etp_sh[7]),
          Tq8=__int_as_float(etp_sh[8]),  Tq9=__int_as_float(etp_sh[9]),
          Tq10=__int_as_float(etp_sh[10]), Tq11=__int_as_float(etp_sh[11]),
          Tq12=__int_as_float(etp_sh[12]), Tq13=__int_as_float(etp_sh[13]),
          Tq14=__int_as_float(etp_sh[14]), Tq15=__int_as_float(etp_sh[15]),
          Tq16=__int_as_float(etp_sh[16]), Tq17=__int_as_float(etp_sh[17]);

    float a0 = (s0i == 0) ? 0.f : NEGV, a1 = (s0i == 1) ? 0.f : NEGV;
    float a2 = (s0i == 2) ? 0.f : NEGV, a3 = (s0i == 3) ? 0.f : NEGV;
    float a4 = (s0i == 4) ? 0.f : NEGV, a5 = (s0i == 5) ? 0.f : NEGV;

    float2 xA0,xA1,xA2,yA0,yA1,yA2, xB0,xB1,xB2,yB0,yB1,yB2;
    LOADSTAGE(xA0,xA1,xA2,yA0,yA1,yA2, cbase + 0);
    LOADSTAGE(xB0,xB1,xB2,yB0,yB1,yB2, cbase + 1);
    for (int s = 0; s < CHL; s += 2){
      ASTEP(xA0,xA1,xA2,yA0,yA1,yA2, cbase + s);
      ASTEP(xB0,xB1,xB2,yB0,yB1,yB2, cbase + s + 1);
    }
    float* mrow = crfM + ((size_t)(b * NCH + c) * 6 + s0i) * 6;
    mrow[0] = a0; mrow[1] = a1; mrow[2] = a2;
    mrow[3] = a3; mrow[4] = a4; mrow[5] = a5;
  } else {
    const int g2 = (bx - 96) * 256 + tid;
    const int b = g2 / NCH;
    const int c = g2 % NCH;
    const int* tg = tags + (size_t)b * SS + c * CHL;
    int prev = (c == 0) ? STARTT : tg[-1];
    float acc = 0.f;
    #pragma unroll 4
    for (int s = 0; s < CHL; ++s){
      int ct = tg[s];
      size_t fo = (size_t)(c * CHL + s) * BB * TT + (size_t)b * TT + ct;
      acc += tr_sh[ct * 6 + prev] + featsF[fo] + featsB[fo];
      prev = ct;
    }
    pgold[b * NCH + c] = acc;
  }
}

// ---------------- K3b: combine 16 chunk matrices + finish -------------------
__global__ __launch_bounds__(64) void k_crf_comb(
    const float* __restrict__ crfM, const float* __restrict__ pgold,
    const float* __restrict__ trans, const int* __restrict__ tags,
    float* __restrict__ out){
  const int b = blockIdx.x * 64 + threadIdx.x;
  float v0 = NEGV, v1 = NEGV, v2 = NEGV, v3 = NEGV, v4 = 0.f, v5 = NEGV;
  for (int c = 0; c < NCH; ++c){
    const float* mb = crfM + (size_t)(b * NCH + c) * 36;
    float n[6];
    #pragma unroll
    for (int j = 0; j < 6; ++j){
      float t0 = v0 + mb[0 * 6 + j], t1 = v1 + mb[1 * 6 + j];
      float t2 = v2 + mb[2 * 6 + j], t3 = v3 + mb[3 * 6 + j];
      float t4 = v4 + mb[4 * 6 + j], t5 = v5 + mb[5 * 6 + j];
      float m = fmaxf(fmaxf(fmaxf(t0,t1),fmaxf(t2,t3)),fmaxf(t4,t5));
      float s = __expf(t0-m)+__expf(t1-m)+__expf(t2-m)
              + __expf(t3-m)+__expf(t4-m)+__expf(t5-m);
      n[j] = m + __logf(s);
    }
    v0 = n[0]; v1 = n[1]; v2 = n[2]; v3 = n[3]; v4 = n[4]; v5 = n[5];
  }
  float z0 = v0 + trans[30], z1 = v1 + trans[31], z2 = v2 + trans[32];
  float z3 = v3 + trans[33], z4 = v4 + trans[34], z5 = v5 + trans[35];
  float M2 = fmaxf(fmaxf(fmaxf(z0,z1),fmaxf(z2,z3)),fmaxf(z4,z5));
  float ss = __expf(z0-M2)+__expf(z1-M2)+__expf(z2-M2)
           + __expf(z3-M2)+__expf(z4-M2)+__expf(z5-M2);
  float fwd = M2 + __logf(ss);

  float gold = trans[STOPT * 6 + tags[(size_t)b * SS + SS - 1]];
  #pragma unroll
  for (int c = 0; c < NCH; ++c) gold += pgold[b * NCH + c];
  out[b] = fwd - gold;
}

// ---------------- launch -----------------------------------------------------
extern "C" void kernel_launch(void* const* d_in, const int* in_sizes, int n_in,
                              void* d_out, int out_size, void* d_ws, size_t ws_size,
                              hipStream_t stream){
  const int*   sentence = (const int*)  d_in[0];
  const int*   tags     = (const int*)  d_in[1];
  const float* emb      = (const float*)d_in[2];
  const float* w_ih_f   = (const float*)d_in[3];
  const float* w_hh_f   = (const float*)d_in[4];
  const float* b_ih_f   = (const float*)d_in[5];
  const float* b_hh_f   = (const float*)d_in[6];
  const float* w_ih_b   = (const float*)d_in[7];
  const float* w_hh_b   = (const float*)d_in[8];
  const float* b_ih_b   = (const float*)d_in[9];
  const float* b_hh_b   = (const float*)d_in[10];
  const float* h0       = (const float*)d_in[11];
  const float* c0       = (const float*)d_in[12];
  const float* w_out    = (const float*)d_in[13];
  const float* b_out    = (const float*)d_in[14];
  const float* trans    = (const float*)d_in[15];
  float* out = (float*)d_out;

  float* ws = (float*)d_ws;
  float* vxg    = ws;                                 // [2][8000][300] (permuted)
  float* featsF = vxg + (size_t)2 * VOCABN * G4;      // [512][256][6]
  float* featsB = featsF + (size_t)SS * BB * TT;      // [512][256][6]
  float* crfM   = featsB + (size_t)SS * BB * TT;      // [256][16][6][6]
  float* pgold  = crfM + (size_t)BB * NCH * 36;       // [256][16]

  k_gemm<<<2 * 125, 256, 0, stream>>>(emb, w_ih_f, w_ih_b,
                                      b_ih_f, b_hh_f, b_ih_b, b_hh_b, vxg);
  k_lstm<<<32, 640, 0, stream>>>(sentence, vxg, w_hh_f, w_hh_b, h0, c0, w_out, b_out,
                                 featsF, featsB);
  k_crf_scan<<<96 + 16, 256, 0, stream>>>(featsF, featsB, trans, tags, crfM, pgold);
  k_crf_comb<<<BB / 64, 64, 0, stream>>>(crfM, pgold, trans, tags, out);
}